// Round 24
// baseline (484.463 us; speedup 1.0000x reference)
//
#include <hip/hip_runtime.h>
#include <hip/hip_bf16.h>
#include <math.h>

#define B_     64
#define NSM_   400
#define NLG_   196
#define SM_    512
#define LG_    1024
#define H_     16
#define DH_    64
#define INNER_ 1024
#define SSTR   424    // S row stride (f32)
#define PSTR   424    // p row stride (bf16, global)

typedef __attribute__((ext_vector_type(8))) short bf16x8;
typedef __attribute__((ext_vector_type(8))) unsigned short u16x8;
typedef __attribute__((ext_vector_type(4))) float f32x4;

__device__ __forceinline__ unsigned short f2b(float f) {
  unsigned u = __float_as_uint(f);
  u = u + 0x7FFFu + ((u >> 16) & 1u);   // RNE
  return (unsigned short)(u >> 16);
}
__device__ __forceinline__ f32x4 zero4() {
  f32x4 a; a[0] = 0.f; a[1] = 0.f; a[2] = 0.f; a[3] = 0.f; return a;
}

// ============================ setup kernels ================================

// setup1 = weight transposes (128x64 tiles) / straight copies + token pass
struct CC2 { const float* tok; float* out; unsigned short* abf; float* cls;
             unsigned short* clsb; int Np1, nf4, shift, tot4; };
// dstT: transposed [Ntiles*64][K] out (or null); dstS: straight [K][1024] out (or null)
struct WTDesc { const float* src; unsigned short* dstT; unsigned short* dstS;
                int K, Ntiles, srcStride, colOff; };
struct WTArgs { WTDesc d[12]; int cum[13]; };
__global__ __launch_bounds__(256) void setup1(CC2 ca, CC2 cb, WTArgs W, int nw,
                                              unsigned short* zb) {
  __shared__ unsigned short tile[128][68];   // 128(k) x 64(n), 8B-aligned rows
  const int tid = threadIdx.x;
  if (blockIdx.x == 0) {
    ushort4 z; z.x = 0; z.y = 0; z.z = 0; z.w = 0;
    ((ushort4*)zb)[tid] = z;                 // 1024-short zero row
  }
  if ((int)blockIdx.x < nw) {
    int bx = blockIdx.x, di = 0;
    while (bx >= W.cum[di + 1]) di++;
    int local = bx - W.cum[di];
    WTDesc g = W.d[di];
    int tn = g.Ntiles;
    if (!g.dstT) {
      // pure straight conv-copy (64-k blocks, no LDS)
      int tpl = tn * (g.K >> 6);
      int layer = local / tpl, rem = local % tpl;
      int kt = (rem / tn) * 64, nt = (rem % tn) * 64;
      const float* wp = g.src + (size_t)layer * g.K * g.srcStride;
      unsigned short* dS = g.dstS + (size_t)layer * g.K * 1024;
#pragma unroll
      for (int p = 0; p < 4; p++) {
        int r = (tid >> 4) + p * 16;
        int c = (tid & 15) * 4;
        const f32x4 v = __builtin_nontemporal_load(
            (const f32x4*)&wp[(size_t)(kt + r) * g.srcStride + g.colOff + nt + c]);
        ushort4 w4;
        w4.x = f2b(v.x); w4.y = f2b(v.y); w4.z = f2b(v.z); w4.w = f2b(v.w);
        *(ushort4*)&dS[(size_t)(kt + r) * 1024 + nt + c] = w4;
      }
    } else {
      // transpose: 128(k) x 64(n) tile -> 256B-contiguous output row chunks
      int tpl = tn * (g.K >> 7);
      int layer = local / tpl, rem = local % tpl;
      int kt = (rem / tn) * 128, nt = (rem % tn) * 64;
      const float* wp = g.src + (size_t)layer * g.K * g.srcStride;
      unsigned short* op = g.dstT + (size_t)layer * (g.Ntiles * 64) * g.K;
#pragma unroll
      for (int p = 0; p < 8; p++) {
        int r = (tid >> 4) + p * 16;     // k-local 0..127
        int c = (tid & 15) * 4;          // n-local
        const f32x4 v = __builtin_nontemporal_load(
            (const f32x4*)&wp[(size_t)(kt + r) * g.srcStride + g.colOff + nt + c]);
        ushort4 w4;
        w4.x = f2b(v.x); w4.y = f2b(v.y); w4.z = f2b(v.z); w4.w = f2b(v.w);
        *(ushort4*)&tile[r][c] = w4;
      }
      __syncthreads();
      const int r2 = tid >> 2, kseg = tid & 3;   // r2: n 0..63; kseg: 32-k chunk
      unsigned short* orow = &op[(size_t)(nt + r2) * g.K + kt + kseg * 32];
#pragma unroll
      for (int s = 0; s < 4; s++) {
        u16x8 v;
#pragma unroll
        for (int i = 0; i < 8; i++) v[i] = tile[kseg * 32 + s * 8 + i][r2];
        *(u16x8*)&orow[s * 8] = v;
      }
    }
  } else {
    // ---- token pass: f32 copy to out (non-temporal), patches->bf16, cls -> f32+bf16
    const int nblk = gridDim.x - nw;
    const int total = ca.tot4 + cb.tot4;
    for (int i = ((int)blockIdx.x - nw) * 256 + tid; i < total; i += nblk * 256) {
      CC2 g; int idx;
      if (i < ca.tot4) { g = ca; idx = i; } else { g = cb; idx = i - ca.tot4; }
      int rowg = idx >> g.shift, t = idx & ((1 << g.shift) - 1);
      int bb = rowg / g.Np1, row = rowg - bb * g.Np1;
      const f32x4 v = __builtin_nontemporal_load(&((const f32x4*)g.tok)[idx]);
      __builtin_nontemporal_store(v, &((f32x4*)g.out)[idx]);
      ushort4 w2; w2.x = f2b(v.x); w2.y = f2b(v.y); w2.z = f2b(v.z); w2.w = f2b(v.w);
      if (row > 0) {
        ((ushort4*)g.abf)[(size_t)(bb * (g.Np1 - 1) + row - 1) * g.nf4 + t] = w2;
      } else {
        ((f32x4*)g.cls)[(size_t)bb * g.nf4 + t] = v;
        ((ushort4*)g.clsb)[(size_t)bb * g.nf4 + t] = w2;
      }
    }
  }
}

// setup2 = x^T transposes, 128(j) x 64(c) tiles, 256B write chunks
struct TXArgs { const unsigned short* xbf; unsigned short* xT; int Nctx, dout, xstride, nx, ny, nblk; };
__global__ __launch_bounds__(256) void setup2(TXArgs ta, TXArgs tb) {
  __shared__ unsigned short tile[128][68];
  TXArgs g; int bx = blockIdx.x;
  if (bx < ta.nblk) { g = ta; } else { g = tb; bx -= ta.nblk; }
  int cx = bx % g.nx; int rem = bx / g.nx;
  int jy = rem % g.ny; int b = rem / g.ny;
  int jt = jy * 128, ct = cx * 64;
  const int tid = threadIdx.x;
#pragma unroll
  for (int p = 0; p < 8; p++) {
    int row = (tid >> 4) + p * 16;   // j-local 0..127
    int c = (tid & 15) * 4;          // c-local
    int j = jt + row;
    ushort4 v;
    if (j < g.Nctx) v = *(const ushort4*)&g.xbf[((size_t)b * g.Nctx + j) * g.dout + ct + c];
    else { v.x = 0; v.y = 0; v.z = 0; v.w = 0; }
    *(ushort4*)&tile[row][c] = v;
  }
  __syncthreads();
  const int r2 = tid >> 2, kseg = tid & 3;
  if (jt + kseg * 32 + 32 <= g.xstride) {    // xstride % 32 == 0 -> exact guard
    unsigned short* orow = &g.xT[((size_t)b * g.dout + ct + r2) * g.xstride + jt + kseg * 32];
#pragma unroll
    for (int s = 0; s < 4; s++) {
      u16x8 v;
#pragma unroll
      for (int i = 0; i < 8; i++) v[i] = tile[kseg * 32 + s * 8 + i][r2];
      *(u16x8*)&orow[s * 8] = v;
    }
  }
}

// ========== wide small GEMM: M=64, one 16-col tile per 256-thr block =======
struct SGDesc {
  const unsigned short* A; const unsigned short* WT; const float* bias;
  float* Cf; unsigned short* Cbf; const float* Rf;
  int K, N;
  float* outF; int ostride;
};
struct SGArgs { SGDesc d[4]; int cum[5]; int nd; };
__global__ __launch_bounds__(256) void sg_wide(SGArgs W) {
  int bx = blockIdx.x, di = 0;
  while (di < W.nd - 1 && bx >= W.cum[di + 1]) di++;
  SGDesc g = W.d[di];
  const int n0 = (bx - W.cum[di]) * 16;
  const int tid = threadIdx.x;
  const int lane = tid & 63, mt = tid >> 6;
  const int r16 = lane & 15, kv8 = (lane >> 4) * 8;
  f32x4 acc0 = zero4(), acc1 = zero4();
  const unsigned short* wp = &g.WT[(size_t)(n0 + r16) * g.K + kv8];
  const unsigned short* ap = &g.A[(size_t)(mt * 16 + r16) * g.K + kv8];
  const int K = g.K;
#pragma unroll 2
  for (int k0 = 0; k0 < K; k0 += 64) {
    acc0 = __builtin_amdgcn_mfma_f32_16x16x32_bf16(*(const bf16x8*)&ap[k0],
                                                   *(const bf16x8*)&wp[k0], acc0, 0, 0, 0);
    acc1 = __builtin_amdgcn_mfma_f32_16x16x32_bf16(*(const bf16x8*)&ap[k0 + 32],
                                                   *(const bf16x8*)&wp[k0 + 32], acc1, 0, 0, 0);
  }
  const int rbase = (lane >> 4) * 4;
#pragma unroll
  for (int rr = 0; rr < 4; rr++) {
    int r = mt * 16 + rbase + rr, c = n0 + r16;
    float v = acc0[rr] + acc1[rr];
    if (g.bias) v += g.bias[c];
    if (g.Rf) v += g.Rf[(size_t)r * g.N + c];
    if (g.Cf)  g.Cf[(size_t)r * g.N + c] = v;
    if (g.Cbf) g.Cbf[(size_t)r * g.N + c] = f2b(v);
    if (g.outF) g.outF[(size_t)r * g.ostride + c] = v;
  }
}

// ================= layernorm (+ scatter xn into xT col jcls) ===============
struct LNArgs { const float* x; unsigned short* xnb; const float* ng; const float* nb;
                int dim; unsigned short* xT; int xstr, jcls; };
__global__ __launch_bounds__(256) void ln2(LNArgs la, LNArgs lb) {
  LNArgs g = ((int)blockIdx.x < 64) ? la : lb;
  int b = blockIdx.x & 63, t = threadIdx.x;
  __shared__ float rs[4], rq[4], bc[2];
  const float* xp = g.x + (size_t)b * g.dim;
  float s = 0.f, sq = 0.f;
  for (int c = t; c < g.dim; c += 256) {
    float v = xp[c];
    s += v; sq += v * v;
  }
#pragma unroll
  for (int off = 32; off >= 1; off >>= 1) {
    s += __shfl_down(s, off);
    sq += __shfl_down(sq, off);
  }
  int w = t >> 6;
  if ((t & 63) == 0) { rs[w] = s; rq[w] = sq; }
  __syncthreads();
  if (t == 0) {
    float ts = rs[0] + rs[1] + rs[2] + rs[3];
    float tq = rq[0] + rq[1] + rq[2] + rq[3];
    float mu = ts / g.dim;
    float var = tq / g.dim - mu * mu;
    bc[0] = mu; bc[1] = rsqrtf(var + 1e-5f);
  }
  __syncthreads();
  float mu = bc[0], r = bc[1];
  for (int c = t; c < g.dim; c += 256) {
    unsigned short hv = f2b((xp[c] - mu) * r * g.ng[c] + g.nb[c]);
    g.xnb[(size_t)b * g.dim + c] = hv;
    g.xT[((size_t)b * g.dim + c) * g.xstr + g.jcls] = hv;   // cls as context token
  }
}

// ==================== q~ via MFMA (scale 0.125 folded in) ==================
struct QTArgs { const unsigned short* qb16; const unsigned short* wkvnb;
                unsigned short* qt; int dout, ntiles, nblk; };
__global__ __launch_bounds__(256) void qtilde3(QTArgs ga, QTArgs gb) {
  QTArgs g; int bx = blockIdx.x;
  if (bx < ga.nblk) g = ga; else { g = gb; bx -= ga.nblk; }
  const int h = bx / g.ntiles, nt = bx - h * g.ntiles;
  const int n0 = nt * 16;
  const int tid = threadIdx.x, lane = tid & 63, mt = tid >> 6;
  const int r16 = lane & 15, kv8 = (lane >> 4) * 8;
  const unsigned short* ap = g.qb16 + (size_t)(mt * 16 + r16) * INNER_ + h * 64 + kv8;
  const unsigned short* bp = g.wkvnb + (size_t)(n0 + r16) * 1024 + h * 64 + kv8;
  f32x4 acc0 = zero4(), acc1 = zero4();
  acc0 = __builtin_amdgcn_mfma_f32_16x16x32_bf16(*(const bf16x8*)&ap[0],
                                                 *(const bf16x8*)&bp[0], acc0, 0, 0, 0);
  acc1 = __builtin_amdgcn_mfma_f32_16x16x32_bf16(*(const bf16x8*)&ap[32],
                                                 *(const bf16x8*)&bp[32], acc1, 0, 0, 0);
  const int rbase = (lane >> 4) * 4;
#pragma unroll
  for (int rr = 0; rr < 4; rr++) {
    int b = mt * 16 + rbase + rr;
    g.qt[((size_t)b * 16 + h) * g.dout + n0 + r16] = f2b((acc0[rr] + acc1[rr]) * 0.125f);
  }
}

// ====== S = q~ . x^T (cls row folded in; 4 j-tiles/block; XCD swizzle) =====
struct SArgs { const unsigned short* qt; const unsigned short* xbf;
               const unsigned short* xnb; const unsigned short* zb; float* S;
               int dout, Nctx, ntj, nbj, nblk; };
__global__ __launch_bounds__(256) void s_gemm(SArgs ga, SArgs gb) {
  SArgs g; int bx;
  if ((int)blockIdx.x < ga.nblk) { g = ga; bx = blockIdx.x; }
  else { g = gb; bx = blockIdx.x - ga.nblk; }
  const int per8 = g.nblk >> 3;
  const int logical = (bx & 7) * per8 + (bx >> 3);
  const int b = logical / g.nbj, jq = logical - b * g.nbj;
  const int tid = threadIdx.x, lane = tid & 63, w = tid >> 6;
  const int jt = jq * 4 + w;
  if (jt >= g.ntj) return;
  const int r16 = lane & 15, kv8 = (lane >> 4) * 8;
  const int j = jt * 16 + r16;
  const unsigned short* brow;
  if (j < g.Nctx)       brow = g.xbf + ((size_t)b * g.Nctx + j) * g.dout;
  else if (j == g.Nctx) brow = g.xnb + (size_t)b * g.dout;   // cls token row
  else                  brow = g.zb;                          // zero row
  const unsigned short* ap = g.qt + ((size_t)b * 16 + r16) * g.dout + kv8;
  const unsigned short* bp = brow + kv8;
  f32x4 acc0 = zero4(), acc1 = zero4();
  const int K = g.dout;
#pragma unroll 2
  for (int k0 = 0; k0 < K; k0 += 64) {
    acc0 = __builtin_amdgcn_mfma_f32_16x16x32_bf16(*(const bf16x8*)&ap[k0],
                                                   *(const bf16x8*)&bp[k0], acc0, 0, 0, 0);
    acc1 = __builtin_amdgcn_mfma_f32_16x16x32_bf16(*(const bf16x8*)&ap[k0 + 32],
                                                   *(const bf16x8*)&bp[k0 + 32], acc1, 0, 0, 0);
  }
  const int rbase = (lane >> 4) * 4;
#pragma unroll
  for (int rr = 0; rr < 4; rr++)
    g.S[((size_t)b * 16 + rbase + rr) * SSTR + jt * 16 + r16] = acc0[rr] + acc1[rr];
}

// ================= softmax -> p (once per (b,h); S pre-scaled) =============
struct SMArgs { const float* S; unsigned short* p; int Nk, Npad; };
__global__ __launch_bounds__(256) void softmax_p2(SMArgs ga, SMArgs gb) {
  SMArgs g = blockIdx.z ? gb : ga;
  const int h = blockIdx.x, b = blockIdx.y;
  const int t = threadIdx.x;
  __shared__ float red[4];
  const float* Sp = g.S + ((size_t)b * 16 + h) * SSTR;

  float sraw[2] = {-1e30f, -1e30f};
#pragma unroll
  for (int u2 = 0; u2 < 2; u2++) {
    int j = t + u2 * 256;
    if (j < g.Nk) sraw[u2] = Sp[j];
  }
  float mx = fmaxf(sraw[0], sraw[1]);
#pragma unroll
  for (int o = 32; o >= 1; o >>= 1) mx = fmaxf(mx, __shfl_down(mx, o));
  if ((t & 63) == 0) red[t >> 6] = mx;
  __syncthreads();
  mx = fmaxf(fmaxf(red[0], red[1]), fmaxf(red[2], red[3]));
  __syncthreads();

  float e0 = (t < g.Nk) ? expf(sraw[0] - mx) : 0.f;
  float e1 = (t + 256 < g.Nk) ? expf(sraw[1] - mx) : 0.f;
  float ls = e0 + e1;
#pragma unroll
  for (int o = 32; o >= 1; o >>= 1) ls += __shfl_down(ls, o);
  if ((t & 63) == 0) red[t >> 6] = ls;
  __syncthreads();
  const float denom = red[0] + red[1] + red[2] + red[3];
  const float inv = 1.f / denom;

  unsigned short* pp = g.p + ((size_t)b * 16 + h) * PSTR;
  if (t < g.Nk) pp[t] = f2b(e0 * inv);
  if (t + 256 < g.Nk) pp[t + 256] = f2b(e1 * inv);
  for (int j = g.Nk + t; j < g.Npad; j += 256) pp[j] = 0;
}

// ============ u = p . x (dual-acc), 1D grid + XCD-aware swizzle ============
struct UG { const unsigned short* p; const unsigned short* xT; unsigned short* u;
            int dout, Npad, xstride, ntx; };
__global__ __launch_bounds__(256) void ugemm2(UG ga, UG gb) {
  const int bid = blockIdx.x;
  const int logical = (bid & 7) * 192 + (bid >> 3);
  const int b = logical / 24;
  int x = logical - b * 24;
  UG g;
  if (x < ga.ntx) g = ga; else { g = gb; x -= ga.ntx; }
  const int tid = threadIdx.x, lane = tid & 63, w = tid >> 6;
  const int c0 = x * 64 + w * 16;
  const int r16 = lane & 15, kv8 = (lane >> 4) * 8, rbase = (lane >> 4) * 4;
  const unsigned short* ap = g.p + ((size_t)b * 16 + r16) * PSTR + kv8;
  const unsigned short* bp = g.xT + ((size_t)b * g.dout + c0 + r16) * g.xstride + kv8;
  f32x4 acc0 = zero4(), acc1 = zero4();
  const int Kp = g.Npad;
  int k0 = 0;
  for (; k0 + 64 <= Kp; k0 += 64) {
    acc0 = __builtin_amdgcn_mfma_f32_16x16x32_bf16(*(const bf16x8*)&ap[k0],
                                                   *(const bf16x8*)&bp[k0], acc0, 0, 0, 0);
    acc1 = __builtin_amdgcn_mfma_f32_16x16x32_bf16(*(const bf16x8*)&ap[k0 + 32],
                                                   *(const bf16x8*)&bp[k0 + 32], acc1, 0, 0, 0);
  }
  if (k0 < Kp)
    acc0 = __builtin_amdgcn_mfma_f32_16x16x32_bf16(*(const bf16x8*)&ap[k0],
                                                   *(const bf16x8*)&bp[k0], acc0, 0, 0, 0);
#pragma unroll
  for (int rr = 0; rr < 4; rr++)
    g.u[((size_t)b * 16 + rbase + rr) * g.dout + c0 + r16] = f2b(acc0[rr] + acc1[rr]);
}

// ==================== o = u.Wv (4 waves/block; cls folded into u) ==========
struct OArgs {
  const unsigned short* u; const unsigned short* WTv; unsigned short* ob; int dout;
};
__global__ __launch_bounds__(256) void ogemm_w(OArgs ga, OArgs gb) {
  OArgs g; int bx = blockIdx.x;
  if (bx < 64) { g = ga; } else { g = gb; bx -= 64; }
  const int h = bx >> 2, dt = bx & 3;
  const int tid = threadIdx.x, lane = tid & 63, mt = tid >> 6;
  const int r16 = lane & 15, kv8 = (lane >> 4) * 8;
  const int dout = g.dout;
  f32x4 acc0 = zero4(), acc1 = zero4();
  const unsigned short* wp = &g.WTv[(size_t)(h * 64 + dt * 16 + r16) * dout + kv8];
  const unsigned short* up = &g.u[((size_t)(mt * 16 + r16) * 16 + h) * dout + kv8];
#pragma unroll 2
  for (int k0 = 0; k0 < dout; k0 += 64) {
    acc0 = __builtin_amdgcn_mfma_f32_16x16x32_bf16(*(const bf16x8*)&up[k0],
                                                   *(const bf16x8*)&wp[k0], acc0, 0, 0, 0);
    acc1 = __builtin_amdgcn_mfma_f32_16x16x32_bf16(*(const bf16x8*)&up[k0 + 32],
                                                   *(const bf16x8*)&wp[k0 + 32], acc1, 0, 0, 0);
  }
  const int rbase = (lane >> 4) * 4;
#pragma unroll
  for (int rr = 0; rr < 4; rr++) {
    int bi = mt * 16 + rbase + rr;
    int d = h * 64 + dt * 16 + r16;
    g.ob[(size_t)bi * INNER_ + d] = f2b(acc0[rr] + acc1[rr]);
  }
}

// ================================ host =====================================
extern "C" void kernel_launch(void* const* d_in, const int* in_sizes, int n_in,
                              void* d_out, int out_size, void* d_ws, size_t ws_size,
                              hipStream_t stream) {
  const float* sm_tokens = (const float*)d_in[0];
  const float* lg_tokens = (const float*)d_in[1];
  const float* a_pin_w  = (const float*)d_in[2];  const float* a_pin_b  = (const float*)d_in[3];
  const float* a_ng     = (const float*)d_in[4];  const float* a_nb     = (const float*)d_in[5];
  const float* a_wq     = (const float*)d_in[6];  const float* a_wkv    = (const float*)d_in[7];
  const float* a_wo     = (const float*)d_in[8];  const float* a_wob    = (const float*)d_in[9];
  const float* a_pout_w = (const float*)d_in[10]; const float* a_pout_b = (const float*)d_in[11];
  const float* b_pin_w  = (const float*)d_in[12]; const float* b_pin_b  = (const float*)d_in[13];
  const float* b_ng     = (const float*)d_in[14]; const float* b_nb     = (const float*)d_in[15];
  const float* b_wq     = (const float*)d_in[16]; const float* b_wkv    = (const float*)d_in[17];
  const float* b_wo     = (const float*)d_in[18]; const float* b_wob    = (const float*)d_in[19];
  const float* b_pout_w = (const float*)d_in[20]; const float* b_pout_b = (const float*)d_in[21];

  float* out = (float*)d_out;
  char* ws = (char*)d_ws;
  size_t off = 0;
  auto alloc = [&](size_t bytes) -> void* {
    void* pt = ws + off;
    off += (bytes + 255) & ~(size_t)255;
    return pt;
  };
  unsigned short* Abf_lg = (unsigned short*)alloc(((size_t)B_ * NLG_ + 32) * LG_ * 2);
  unsigned short* Abf_sm = (unsigned short*)alloc(((size_t)B_ * NSM_ + 32) * SM_ * 2);
  unsigned short* xT_lg  = (unsigned short*)alloc((size_t)B_ * LG_ * 224 * 2);
  unsigned short* xT_sm  = (unsigned short*)alloc((size_t)B_ * SM_ * 416 * 2);
  unsigned short* WTv_a  = (unsigned short*)alloc((size_t)4 * 1024 * LG_ * 2);
  unsigned short* WTv_b  = (unsigned short*)alloc((size_t)4 * 1024 * SM_ * 2);
  unsigned short* wkvnb_a = (unsigned short*)alloc((size_t)4 * LG_ * 1024 * 2);
  unsigned short* wkvnb_b = (unsigned short*)alloc((size_t)4 * SM_ * 1024 * 2);
  unsigned short* WTpin_a = (unsigned short*)alloc((size_t)4 * SM_ * LG_ * 2);
  unsigned short* WTpin_b = (unsigned short*)alloc((size_t)4 * LG_ * SM_ * 2);
  unsigned short* WTwq_a  = (unsigned short*)alloc((size_t)4 * LG_ * INNER_ * 2);
  unsigned short* WTwq_b  = (unsigned short*)alloc((size_t)4 * SM_ * INNER_ * 2);
  unsigned short* WTwo_a  = (unsigned short*)alloc((size_t)4 * INNER_ * LG_ * 2);
  unsigned short* WTwo_b  = (unsigned short*)alloc((size_t)4 * INNER_ * SM_ * 2);
  unsigned short* WTpout_a = (unsigned short*)alloc((size_t)4 * LG_ * SM_ * 2);
  unsigned short* WTpout_b = (unsigned short*)alloc((size_t)4 * SM_ * LG_ * 2);
  unsigned short* qt_a = (unsigned short*)alloc((size_t)B_ * 16 * LG_ * 2);
  unsigned short* qt_b = (unsigned short*)alloc((size_t)B_ * 16 * SM_ * 2);
  float* S_a = (float*)alloc((size_t)B_ * 16 * SSTR * 4);
  float* S_b = (float*)alloc((size_t)B_ * 16 * SSTR * 4);
  unsigned short* p_a = (unsigned short*)alloc((size_t)B_ * 16 * PSTR * 2);
  unsigned short* p_b = (unsigned short*)alloc((size_t)B_ * 16 * PSTR * 2);
  unsigned short* u_a  = (unsigned short*)alloc((size_t)B_ * 16 * LG_ * 2);
  unsigned short* u_b  = (unsigned short*)alloc((size_t)B_ * 16 * SM_ * 2);
  float* cls_sm = (float*)alloc((size_t)B_ * SM_ * 4);
  float* cls_lg = (float*)alloc((size_t)B_ * LG_ * 4);
  unsigned short* clsb_sm = (unsigned short*)alloc((size_t)B_ * SM_ * 2);
  unsigned short* clsb_lg = (unsigned short*)alloc((size_t)B_ * LG_ * 2);
  float* xbuf_a = (float*)alloc((size_t)B_ * LG_ * 4);
  float* xbuf_b = (float*)alloc((size_t)B_ * SM_ * 4);
  unsigned short* xnb_a = (unsigned short*)alloc((size_t)B_ * LG_ * 2);
  unsigned short* xnb_b = (unsigned short*)alloc((size_t)B_ * SM_ * 2);
  unsigned short* qb16_a = (unsigned short*)alloc((size_t)B_ * INNER_ * 2);
  unsigned short* qb16_b = (unsigned short*)alloc((size_t)B_ * INNER_ * 2);
  unsigned short* obufb_a = (unsigned short*)alloc((size_t)B_ * INNER_ * 2);
  unsigned short* obufb_b = (unsigned short*)alloc((size_t)B_ * INNER_ * 2);
  unsigned short* t1b_a = (unsigned short*)alloc((size_t)B_ * LG_ * 2);
  unsigned short* t1b_b = (unsigned short*)alloc((size_t)B_ * SM_ * 2);
  unsigned short* zb = (unsigned short*)alloc(1024 * 2);   // zero row
  (void)ws_size; (void)in_sizes; (void)n_in; (void)out_size;

  const size_t sm_elems = (size_t)B_ * (NSM_ + 1) * SM_;

  // ---- setup1: weight transposes/copies + token pass (one dispatch)
  CC2 ca{sm_tokens, out, Abf_sm, cls_sm, clsb_sm, NSM_ + 1, SM_ / 4, 7,
         (int)(sm_elems / 4)};
  CC2 cb{lg_tokens, out + sm_elems, Abf_lg, cls_lg, clsb_lg, NLG_ + 1, LG_ / 4, 8,
         (int)((size_t)B_ * (NLG_ + 1) * LG_ / 4)};
  WTArgs W;
  // {src, dstT, dstS, K, Ntiles, srcStride, colOff}
  W.d[0]  = {a_wkv,    nullptr,  wkvnb_a, LG_,   16, 2048, 0};     // K-half straight copy
  W.d[1]  = {a_wkv,    WTv_a,    nullptr, LG_,   16, 2048, 1024};  // V-half transpose
  W.d[2]  = {b_wkv,    nullptr,  wkvnb_b, SM_,   16, 2048, 0};
  W.d[3]  = {b_wkv,    WTv_b,    nullptr, SM_,   16, 2048, 1024};
  W.d[4]  = {a_pin_w,  WTpin_a,  nullptr, SM_,   16, 1024, 0};
  W.d[5]  = {b_pin_w,  WTpin_b,  nullptr, LG_,    8,  512, 0};
  W.d[6]  = {a_wq,     WTwq_a,   nullptr, LG_,   16, 1024, 0};
  W.d[7]  = {b_wq,     WTwq_b,   nullptr, SM_,   16, 1024, 0};
  W.d[8]  = {a_wo,     WTwo_a,   nullptr, INNER_,16, 1024, 0};
  W.d[9]  = {b_wo,     WTwo_b,   nullptr, INNER_, 8,  512, 0};
  W.d[10] = {a_pout_w, WTpout_a, nullptr, LG_,    8,  512, 0};
  W.d[11] = {b_pout_w, WTpout_b, nullptr, SM_,   16, 1024, 0};
  W.cum[0] = 0;
  for (int i = 0; i < 12; i++) {
    int kb = W.d[i].dstT ? (W.d[i].K / 128) : (W.d[i].K / 64);
    W.cum[i + 1] = W.cum[i] + kb * W.d[i].Ntiles * 4;
  }
  setup1<<<W.cum[12] + 2048, 256, 0, stream>>>(ca, cb, W, W.cum[12], zb);
  // ---- setup2: x^T (needs Abf from setup1); 128-j tiles
  TXArgs txa{Abf_lg, xT_lg, NLG_, LG_, 224, LG_ / 64, 2, B_ * (LG_ / 64) * 2};
  TXArgs txb{Abf_sm, xT_sm, NSM_, SM_, 416, SM_ / 64, 4, B_ * (SM_ / 64) * 4};
  setup2<<<txa.nblk + txb.nblk, 256, 0, stream>>>(txa, txb);

  for (int l = 0; l < 4; l++) {
    const unsigned short* WTpin_al = WTpin_a + (size_t)l * SM_ * LG_;
    const unsigned short* WTpin_bl = WTpin_b + (size_t)l * LG_ * SM_;
    const unsigned short* WTwq_al  = WTwq_a  + (size_t)l * LG_ * INNER_;
    const unsigned short* WTwq_bl  = WTwq_b  + (size_t)l * SM_ * INNER_;
    const unsigned short* WTv_al   = WTv_a   + (size_t)l * 1024 * LG_;
    const unsigned short* WTv_bl   = WTv_b   + (size_t)l * 1024 * SM_;
    const unsigned short* wkvnb_al = wkvnb_a + (size_t)l * LG_ * 1024;
    const unsigned short* wkvnb_bl = wkvnb_b + (size_t)l * SM_ * 1024;
    const unsigned short* WTwo_al  = WTwo_a  + (size_t)l * INNER_ * LG_;
    const unsigned short* WTwo_bl  = WTwo_b  + (size_t)l * INNER_ * SM_;
    const unsigned short* WTpout_al = WTpout_a + (size_t)l * LG_ * SM_;
    const unsigned short* WTpout_bl = WTpout_b + (size_t)l * SM_ * LG_;

    // pin
    SGArgs Gp; Gp.nd = 2;
    Gp.d[0] = {clsb_sm, WTpin_al, a_pin_b + (size_t)l * LG_, xbuf_a, nullptr, nullptr, SM_, LG_, nullptr, 0};
    Gp.d[1] = {clsb_lg, WTpin_bl, b_pin_b + (size_t)l * SM_, xbuf_b, nullptr, nullptr, LG_, SM_, nullptr, 0};
    Gp.cum[0] = 0; Gp.cum[1] = LG_ / 16; Gp.cum[2] = LG_ / 16 + SM_ / 16;
    sg_wide<<<Gp.cum[2], 256, 0, stream>>>(Gp);
    // ln (+ scatter xn into xT col Nctx)
    LNArgs la{xbuf_a, xnb_a, a_ng + (size_t)l * LG_, a_nb + (size_t)l * LG_, LG_, xT_lg, 224, NLG_};
    LNArgs lb{xbuf_b, xnb_b, b_ng + (size_t)l * SM_, b_nb + (size_t)l * SM_, SM_, xT_sm, 416, NSM_};
    ln2<<<128, 256, 0, stream>>>(la, lb);
    // q only (bf16)
    SGArgs Gq; Gq.nd = 2;
    Gq.d[0] = {xnb_a, WTwq_al, nullptr, nullptr, qb16_a, nullptr, LG_, INNER_, nullptr, 0};
    Gq.d[1] = {xnb_b, WTwq_bl, nullptr, nullptr, qb16_b, nullptr, SM_, INNER_, nullptr, 0};
    Gq.cum[0] = 0; Gq.cum[1] = 64; Gq.cum[2] = 128;
    sg_wide<<<128, 256, 0, stream>>>(Gq);
    // q~ (MFMA over bf16 straight wkv K-half; 0.125 folded)
    QTArgs qa{qb16_a, wkvnb_al, qt_a, LG_, LG_ / 16, 16 * (LG_ / 16)};
    QTArgs qb{qb16_b, wkvnb_bl, qt_b, SM_, SM_ / 16, 16 * (SM_ / 16)};
    qtilde3<<<qa.nblk + qb.nblk, 256, 0, stream>>>(qa, qb);
    // S = q~ . x^T  (cls row included; XCD-swizzled)
    SArgs sa{qt_a, Abf_lg, xnb_a, zb, S_a, LG_, NLG_, 14, 4, B_ * 4};
    SArgs sb{qt_b, Abf_sm, xnb_b, zb, S_b, SM_, NSM_, 26, 7, B_ * 7};
    s_gemm<<<sa.nblk + sb.nblk, 256, 0, stream>>>(sa, sb);
    // softmax -> p (once per (b,h); cls = row Nctx)
    SMArgs ma{S_a, p_a, NLG_ + 1, 224};
    SMArgs mb{S_b, p_b, NSM_ + 1, 416};
    softmax_p2<<<dim3(H_, B_, 2), 256, 0, stream>>>(ma, mb);
    // u = p . x  (1D grid, XCD-swizzled; includes cls term)
    UG ua{p_a, xT_lg, u_a, LG_, 224, 224, LG_ / 64};
    UG ub{p_b, xT_sm, u_b, SM_, 416, 416, SM_ / 64};
    ugemm2<<<1536, 256, 0, stream>>>(ua, ub);
    // o = u . Wv
    OArgs oa{u_a, WTv_al, obufb_a, LG_};
    OArgs ob{u_b, WTv_bl, obufb_b, SM_};
    ogemm_w<<<128, 256, 0, stream>>>(oa, ob);
    // wo
    SGArgs Gw; Gw.nd = 2;
    Gw.d[0] = {obufb_a, WTwo_al, a_wob + (size_t)l * LG_, nullptr, t1b_a, nullptr, INNER_, LG_, nullptr, 0};
    Gw.d[1] = {obufb_b, WTwo_bl, b_wob + (size_t)l * SM_, nullptr, t1b_b, nullptr, INNER_, SM_, nullptr, 0};
    Gw.cum[0] = 0; Gw.cum[1] = LG_ / 16; Gw.cum[2] = LG_ / 16 + SM_ / 16;
    sg_wide<<<Gw.cum[2], 256, 0, stream>>>(Gw);
    // pout + residual; on the last layer also write cls rows straight to out
    float* outF_a = (l == 3) ? out : nullptr;
    float* outF_b = (l == 3) ? out + sm_elems : nullptr;
    SGArgs Gr; Gr.nd = 2;
    Gr.d[0] = {t1b_a, WTpout_al, a_pout_b + (size_t)l * SM_, cls_sm, clsb_sm, cls_sm, LG_, SM_,
               outF_a, (NSM_ + 1) * SM_};
    Gr.d[1] = {t1b_b, WTpout_bl, b_pout_b + (size_t)l * LG_, cls_lg, clsb_lg, cls_lg, SM_, LG_,
               outF_b, (NLG_ + 1) * LG_};
    Gr.cum[0] = 0; Gr.cum[1] = SM_ / 16; Gr.cum[2] = SM_ / 16 + LG_ / 16;
    sg_wide<<<Gr.cum[2], 256, 0, stream>>>(Gr);
  }
}

// Round 25
// 473.257 us; speedup vs baseline: 1.0237x; 1.0237x over previous
//
#include <hip/hip_runtime.h>
#include <hip/hip_bf16.h>
#include <math.h>

#define B_     64
#define NSM_   400
#define NLG_   196
#define SM_    512
#define LG_    1024
#define H_     16
#define DH_    64
#define INNER_ 1024
#define SSTR   424    // S row stride (f32)
#define PSTR   424    // p row stride (bf16, global)

typedef __attribute__((ext_vector_type(8))) short bf16x8;
typedef __attribute__((ext_vector_type(8))) unsigned short u16x8;
typedef __attribute__((ext_vector_type(4))) float f32x4;

__device__ __forceinline__ unsigned short f2b(float f) {
  unsigned u = __float_as_uint(f);
  u = u + 0x7FFFu + ((u >> 16) & 1u);   // RNE
  return (unsigned short)(u >> 16);
}
__device__ __forceinline__ f32x4 zero4() {
  f32x4 a; a[0] = 0.f; a[1] = 0.f; a[2] = 0.f; a[3] = 0.f; return a;
}

// ============================ setup kernels ================================

// setup1 = weight transposes/copies + token pass (nt copy) + zero row init
struct CC2 { const float* tok; float* out; unsigned short* abf; float* cls;
             unsigned short* clsb; int Np1, nf4, shift, tot4; };
// dstT: transposed [Ntiles*64][K] out (or null); dstS: straight [K][1024] out (or null)
struct WTDesc { const float* src; unsigned short* dstT; unsigned short* dstS;
                int K, Ntiles, srcStride, colOff; };
struct WTArgs { WTDesc d[12]; int cum[13]; };
__global__ __launch_bounds__(256) void setup1(CC2 ca, CC2 cb, WTArgs W, int nw,
                                              unsigned short* zb) {
  __shared__ unsigned short tile[64][68];   // 136B rows: 8B-aligned
  const int tid = threadIdx.x;
  if (blockIdx.x == 0) {
    ushort4 z; z.x = 0; z.y = 0; z.z = 0; z.w = 0;
    ((ushort4*)zb)[tid] = z;                 // 1024-short zero row
  }
  if ((int)blockIdx.x < nw) {
    int bx = blockIdx.x, di = 0;
    while (bx >= W.cum[di + 1]) di++;
    int local = bx - W.cum[di];
    WTDesc g = W.d[di];
    int tn = g.Ntiles;
    int tpl = tn * (g.K >> 6);
    int layer = local / tpl, rem = local % tpl;
    int kt = (rem / tn) * 64, nt = (rem % tn) * 64;
    const float* wp = g.src + (size_t)layer * g.K * g.srcStride;
    unsigned short* dS = g.dstS ? g.dstS + (size_t)layer * g.K * 1024 : nullptr;
    if (!g.dstT) {
      // pure straight conv-copy (no LDS)
#pragma unroll
      for (int p = 0; p < 4; p++) {
        int r = (tid >> 4) + p * 16;
        int c = (tid & 15) * 4;
        const f32x4 v = __builtin_nontemporal_load(
            (const f32x4*)&wp[(size_t)(kt + r) * g.srcStride + g.colOff + nt + c]);
        ushort4 w4;
        w4.x = f2b(v.x); w4.y = f2b(v.y); w4.z = f2b(v.z); w4.w = f2b(v.w);
        *(ushort4*)&dS[(size_t)(kt + r) * 1024 + nt + c] = w4;
      }
    } else {
      unsigned short* op = g.dstT + (size_t)layer * (g.Ntiles * 64) * g.K;
#pragma unroll
      for (int p = 0; p < 4; p++) {
        int r = (tid >> 4) + p * 16;
        int c = (tid & 15) * 4;
        const f32x4 v = __builtin_nontemporal_load(
            (const f32x4*)&wp[(size_t)(kt + r) * g.srcStride + g.colOff + nt + c]);
        ushort4 w4;
        w4.x = f2b(v.x); w4.y = f2b(v.y); w4.z = f2b(v.z); w4.w = f2b(v.w);
        *(ushort4*)&tile[r][c] = w4;
        if (dS) *(ushort4*)&dS[(size_t)(kt + r) * 1024 + nt + c] = w4;
      }
      __syncthreads();
      // coalesced transpose-out: 4-lane cluster writes one contiguous 128B row chunk
      const int r2 = tid >> 2, cseg = tid & 3;
      u16x8 v0, v1;
#pragma unroll
      for (int i = 0; i < 8; i++) v0[i] = tile[cseg * 16 + i][r2];
#pragma unroll
      for (int i = 0; i < 8; i++) v1[i] = tile[cseg * 16 + 8 + i][r2];
      unsigned short* orow = &op[(size_t)(nt + r2) * g.K + kt + cseg * 16];
      *(u16x8*)&orow[0] = v0;
      *(u16x8*)&orow[8] = v1;
    }
  } else {
    // ---- token pass: f32 copy to out (non-temporal), patches->bf16, cls -> f32+bf16
    const int nblk = gridDim.x - nw;
    const int total = ca.tot4 + cb.tot4;
    for (int i = ((int)blockIdx.x - nw) * 256 + tid; i < total; i += nblk * 256) {
      CC2 g; int idx;
      if (i < ca.tot4) { g = ca; idx = i; } else { g = cb; idx = i - ca.tot4; }
      int rowg = idx >> g.shift, t = idx & ((1 << g.shift) - 1);
      int bb = rowg / g.Np1, row = rowg - bb * g.Np1;
      const f32x4 v = __builtin_nontemporal_load(&((const f32x4*)g.tok)[idx]);
      __builtin_nontemporal_store(v, &((f32x4*)g.out)[idx]);
      ushort4 w2; w2.x = f2b(v.x); w2.y = f2b(v.y); w2.z = f2b(v.z); w2.w = f2b(v.w);
      if (row > 0) {
        ((ushort4*)g.abf)[(size_t)(bb * (g.Np1 - 1) + row - 1) * g.nf4 + t] = w2;
      } else {
        ((f32x4*)g.cls)[(size_t)bb * g.nf4 + t] = v;
        ((ushort4*)g.clsb)[(size_t)bb * g.nf4 + t] = w2;
      }
    }
  }
}

// setup2 = x^T transposes (depends on Abf), coalesced writes
struct TXArgs { const unsigned short* xbf; unsigned short* xT; int Nctx, dout, xstride, nx, ny, nblk; };
__global__ __launch_bounds__(256) void setup2(TXArgs ta, TXArgs tb) {
  __shared__ unsigned short tile[64][68];
  TXArgs g; int bx = blockIdx.x;
  if (bx < ta.nblk) { g = ta; } else { g = tb; bx -= ta.nblk; }
  int cx = bx % g.nx; int rem = bx / g.nx;
  int jy = rem % g.ny; int b = rem / g.ny;
  int jt = jy * 64, ct = cx * 64;
  const int tid = threadIdx.x;
#pragma unroll
  for (int p = 0; p < 4; p++) {
    int row = (tid >> 4) + p * 16;   // j-local
    int c = (tid & 15) * 4;          // dout-local
    int j = jt + row;
    ushort4 v;
    if (j < g.Nctx) v = *(const ushort4*)&g.xbf[((size_t)b * g.Nctx + j) * g.dout + ct + c];
    else { v.x = 0; v.y = 0; v.z = 0; v.w = 0; }
    *(ushort4*)&tile[row][c] = v;
  }
  __syncthreads();
  const int r2 = tid >> 2, jseg = tid & 3;
  if (jt + jseg * 16 < g.xstride) {
    u16x8 v0, v1;
#pragma unroll
    for (int i = 0; i < 8; i++) v0[i] = tile[jseg * 16 + i][r2];
#pragma unroll
    for (int i = 0; i < 8; i++) v1[i] = tile[jseg * 16 + 8 + i][r2];
    unsigned short* orow = &g.xT[((size_t)b * g.dout + ct + r2) * g.xstride + jt + jseg * 16];
    *(u16x8*)&orow[0] = v0;
    *(u16x8*)&orow[8] = v1;
  }
}

// ========== wide small GEMM: M=64, one 16-col tile per 256-thr block =======
struct SGDesc {
  const unsigned short* A; const unsigned short* WT; const float* bias;
  float* Cf; unsigned short* Cbf; const float* Rf;
  int K, N;
  float* outF; int ostride;
};
struct SGArgs { SGDesc d[4]; int cum[5]; int nd; };
__global__ __launch_bounds__(256) void sg_wide(SGArgs W) {
  int bx = blockIdx.x, di = 0;
  while (di < W.nd - 1 && bx >= W.cum[di + 1]) di++;
  SGDesc g = W.d[di];
  const int n0 = (bx - W.cum[di]) * 16;
  const int tid = threadIdx.x;
  const int lane = tid & 63, mt = tid >> 6;
  const int r16 = lane & 15, kv8 = (lane >> 4) * 8;
  f32x4 acc0 = zero4(), acc1 = zero4();
  const unsigned short* wp = &g.WT[(size_t)(n0 + r16) * g.K + kv8];
  const unsigned short* ap = &g.A[(size_t)(mt * 16 + r16) * g.K + kv8];
  const int K = g.K;
#pragma unroll 2
  for (int k0 = 0; k0 < K; k0 += 64) {
    acc0 = __builtin_amdgcn_mfma_f32_16x16x32_bf16(*(const bf16x8*)&ap[k0],
                                                   *(const bf16x8*)&wp[k0], acc0, 0, 0, 0);
    acc1 = __builtin_amdgcn_mfma_f32_16x16x32_bf16(*(const bf16x8*)&ap[k0 + 32],
                                                   *(const bf16x8*)&wp[k0 + 32], acc1, 0, 0, 0);
  }
  const int rbase = (lane >> 4) * 4;
#pragma unroll
  for (int rr = 0; rr < 4; rr++) {
    int r = mt * 16 + rbase + rr, c = n0 + r16;
    float v = acc0[rr] + acc1[rr];
    if (g.bias) v += g.bias[c];
    if (g.Rf) v += g.Rf[(size_t)r * g.N + c];
    if (g.Cf)  g.Cf[(size_t)r * g.N + c] = v;
    if (g.Cbf) g.Cbf[(size_t)r * g.N + c] = f2b(v);
    if (g.outF) g.outF[(size_t)r * g.ostride + c] = v;
  }
}

// ================= layernorm (+ scatter xn into xT col jcls) ===============
struct LNArgs { const float* x; unsigned short* xnb; const float* ng; const float* nb;
                int dim; unsigned short* xT; int xstr, jcls; };
__global__ __launch_bounds__(256) void ln2(LNArgs la, LNArgs lb) {
  LNArgs g = ((int)blockIdx.x < 64) ? la : lb;
  int b = blockIdx.x & 63, t = threadIdx.x;
  __shared__ float rs[4], rq[4], bc[2];
  const float* xp = g.x + (size_t)b * g.dim;
  float s = 0.f, sq = 0.f;
  for (int c = t; c < g.dim; c += 256) {
    float v = xp[c];
    s += v; sq += v * v;
  }
#pragma unroll
  for (int off = 32; off >= 1; off >>= 1) {
    s += __shfl_down(s, off);
    sq += __shfl_down(sq, off);
  }
  int w = t >> 6;
  if ((t & 63) == 0) { rs[w] = s; rq[w] = sq; }
  __syncthreads();
  if (t == 0) {
    float ts = rs[0] + rs[1] + rs[2] + rs[3];
    float tq = rq[0] + rq[1] + rq[2] + rq[3];
    float mu = ts / g.dim;
    float var = tq / g.dim - mu * mu;
    bc[0] = mu; bc[1] = rsqrtf(var + 1e-5f);
  }
  __syncthreads();
  float mu = bc[0], r = bc[1];
  for (int c = t; c < g.dim; c += 256) {
    unsigned short hv = f2b((xp[c] - mu) * r * g.ng[c] + g.nb[c]);
    g.xnb[(size_t)b * g.dim + c] = hv;
    g.xT[((size_t)b * g.dim + c) * g.xstr + g.jcls] = hv;   // cls as context token
  }
}

// ==================== q~ via MFMA: q̃_bh = q_h(64x64) @ wkv_rows ============
struct QTArgs { const unsigned short* qb16; const unsigned short* wkvnb;
                unsigned short* qt; int dout, ntiles, nblk; };
__global__ __launch_bounds__(256) void qtilde3(QTArgs ga, QTArgs gb) {
  QTArgs g; int bx = blockIdx.x;
  if (bx < ga.nblk) g = ga; else { g = gb; bx -= ga.nblk; }
  const int h = bx / g.ntiles, nt = bx - h * g.ntiles;
  const int n0 = nt * 16;
  const int tid = threadIdx.x, lane = tid & 63, mt = tid >> 6;
  const int r16 = lane & 15, kv8 = (lane >> 4) * 8;
  const unsigned short* ap = g.qb16 + (size_t)(mt * 16 + r16) * INNER_ + h * 64 + kv8;
  const unsigned short* bp = g.wkvnb + (size_t)(n0 + r16) * 1024 + h * 64 + kv8;
  f32x4 acc0 = zero4(), acc1 = zero4();
  acc0 = __builtin_amdgcn_mfma_f32_16x16x32_bf16(*(const bf16x8*)&ap[0],
                                                 *(const bf16x8*)&bp[0], acc0, 0, 0, 0);
  acc1 = __builtin_amdgcn_mfma_f32_16x16x32_bf16(*(const bf16x8*)&ap[32],
                                                 *(const bf16x8*)&bp[32], acc1, 0, 0, 0);
  const int rbase = (lane >> 4) * 4;
#pragma unroll
  for (int rr = 0; rr < 4; rr++) {
    int b = mt * 16 + rbase + rr;
    g.qt[((size_t)b * 16 + h) * g.dout + n0 + r16] = f2b(acc0[rr] + acc1[rr]);
  }
}

// ====== S = q~ . x^T (cls row folded in; 4 j-tiles/block; XCD swizzle) =====
struct SArgs { const unsigned short* qt; const unsigned short* xbf;
               const unsigned short* xnb; const unsigned short* zb; float* S;
               int dout, Nctx, ntj, nbj, nblk; };
__global__ __launch_bounds__(256) void s_gemm(SArgs ga, SArgs gb) {
  SArgs g; int bx;
  if ((int)blockIdx.x < ga.nblk) { g = ga; bx = blockIdx.x; }
  else { g = gb; bx = blockIdx.x - ga.nblk; }
  const int per8 = g.nblk >> 3;
  const int logical = (bx & 7) * per8 + (bx >> 3);
  const int b = logical / g.nbj, jq = logical - b * g.nbj;
  const int tid = threadIdx.x, lane = tid & 63, w = tid >> 6;
  const int jt = jq * 4 + w;
  if (jt >= g.ntj) return;
  const int r16 = lane & 15, kv8 = (lane >> 4) * 8;
  const int j = jt * 16 + r16;
  const unsigned short* brow;
  if (j < g.Nctx)       brow = g.xbf + ((size_t)b * g.Nctx + j) * g.dout;
  else if (j == g.Nctx) brow = g.xnb + (size_t)b * g.dout;   // cls token row
  else                  brow = g.zb;                          // zero row
  const unsigned short* ap = g.qt + ((size_t)b * 16 + r16) * g.dout + kv8;
  const unsigned short* bp = brow + kv8;
  f32x4 acc0 = zero4(), acc1 = zero4();
  const int K = g.dout;
#pragma unroll 2
  for (int k0 = 0; k0 < K; k0 += 64) {
    acc0 = __builtin_amdgcn_mfma_f32_16x16x32_bf16(*(const bf16x8*)&ap[k0],
                                                   *(const bf16x8*)&bp[k0], acc0, 0, 0, 0);
    acc1 = __builtin_amdgcn_mfma_f32_16x16x32_bf16(*(const bf16x8*)&ap[k0 + 32],
                                                   *(const bf16x8*)&bp[k0 + 32], acc1, 0, 0, 0);
  }
  const int rbase = (lane >> 4) * 4;
#pragma unroll
  for (int rr = 0; rr < 4; rr++)
    g.S[((size_t)b * 16 + rbase + rr) * SSTR + jt * 16 + r16] = acc0[rr] + acc1[rr];
}

// ================= softmax -> p (once per (b,h); cls is row Nctx) ==========
struct SMArgs { const float* S; unsigned short* p; int Nk, Npad; };
__global__ __launch_bounds__(256) void softmax_p2(SMArgs ga, SMArgs gb) {
  SMArgs g = blockIdx.z ? gb : ga;
  const int h = blockIdx.x, b = blockIdx.y;
  const int t = threadIdx.x;
  __shared__ float red[4];
  const float* Sp = g.S + ((size_t)b * 16 + h) * SSTR;

  float sraw[2] = {-1e30f, -1e30f};
#pragma unroll
  for (int u2 = 0; u2 < 2; u2++) {
    int j = t + u2 * 256;
    if (j < g.Nk) sraw[u2] = Sp[j] * 0.125f;
  }
  float mx = fmaxf(sraw[0], sraw[1]);
#pragma unroll
  for (int o = 32; o >= 1; o >>= 1) mx = fmaxf(mx, __shfl_down(mx, o));
  if ((t & 63) == 0) red[t >> 6] = mx;
  __syncthreads();
  mx = fmaxf(fmaxf(red[0], red[1]), fmaxf(red[2], red[3]));
  __syncthreads();

  float e0 = (t < g.Nk) ? expf(sraw[0] - mx) : 0.f;
  float e1 = (t + 256 < g.Nk) ? expf(sraw[1] - mx) : 0.f;
  float ls = e0 + e1;
#pragma unroll
  for (int o = 32; o >= 1; o >>= 1) ls += __shfl_down(ls, o);
  if ((t & 63) == 0) red[t >> 6] = ls;
  __syncthreads();
  const float denom = red[0] + red[1] + red[2] + red[3];
  const float inv = 1.f / denom;

  unsigned short* pp = g.p + ((size_t)b * 16 + h) * PSTR;
  if (t < g.Nk) pp[t] = f2b(e0 * inv);
  if (t + 256 < g.Nk) pp[t + 256] = f2b(e1 * inv);
  for (int j = g.Nk + t; j < g.Npad; j += 256) pp[j] = 0;
}

// ============ u = p . x (dual-acc), 1D grid + XCD-aware swizzle ============
struct UG { const unsigned short* p; const unsigned short* xT; unsigned short* u;
            int dout, Npad, xstride, ntx; };
__global__ __launch_bounds__(256) void ugemm2(UG ga, UG gb) {
  const int bid = blockIdx.x;
  const int logical = (bid & 7) * 192 + (bid >> 3);
  const int b = logical / 24;
  int x = logical - b * 24;
  UG g;
  if (x < ga.ntx) g = ga; else { g = gb; x -= ga.ntx; }
  const int tid = threadIdx.x, lane = tid & 63, w = tid >> 6;
  const int c0 = x * 64 + w * 16;
  const int r16 = lane & 15, kv8 = (lane >> 4) * 8, rbase = (lane >> 4) * 4;
  const unsigned short* ap = g.p + ((size_t)b * 16 + r16) * PSTR + kv8;
  const unsigned short* bp = g.xT + ((size_t)b * g.dout + c0 + r16) * g.xstride + kv8;
  f32x4 acc0 = zero4(), acc1 = zero4();
  const int Kp = g.Npad;
  int k0 = 0;
  for (; k0 + 64 <= Kp; k0 += 64) {
    acc0 = __builtin_amdgcn_mfma_f32_16x16x32_bf16(*(const bf16x8*)&ap[k0],
                                                   *(const bf16x8*)&bp[k0], acc0, 0, 0, 0);
    acc1 = __builtin_amdgcn_mfma_f32_16x16x32_bf16(*(const bf16x8*)&ap[k0 + 32],
                                                   *(const bf16x8*)&bp[k0 + 32], acc1, 0, 0, 0);
  }
  if (k0 < Kp)
    acc0 = __builtin_amdgcn_mfma_f32_16x16x32_bf16(*(const bf16x8*)&ap[k0],
                                                   *(const bf16x8*)&bp[k0], acc0, 0, 0, 0);
#pragma unroll
  for (int rr = 0; rr < 4; rr++)
    g.u[((size_t)b * 16 + rbase + rr) * g.dout + c0 + r16] = f2b(acc0[rr] + acc1[rr]);
}

// ==================== o = u.Wv (4 waves/block; cls folded into u) ==========
struct OArgs {
  const unsigned short* u; const unsigned short* WTv; unsigned short* ob; int dout;
};
__global__ __launch_bounds__(256) void ogemm_w(OArgs ga, OArgs gb) {
  OArgs g; int bx = blockIdx.x;
  if (bx < 64) { g = ga; } else { g = gb; bx -= 64; }
  const int h = bx >> 2, dt = bx & 3;
  const int tid = threadIdx.x, lane = tid & 63, mt = tid >> 6;
  const int r16 = lane & 15, kv8 = (lane >> 4) * 8;
  const int dout = g.dout;
  f32x4 acc0 = zero4(), acc1 = zero4();
  const unsigned short* wp = &g.WTv[(size_t)(h * 64 + dt * 16 + r16) * dout + kv8];
  const unsigned short* up = &g.u[((size_t)(mt * 16 + r16) * 16 + h) * dout + kv8];
#pragma unroll 2
  for (int k0 = 0; k0 < dout; k0 += 64) {
    acc0 = __builtin_amdgcn_mfma_f32_16x16x32_bf16(*(const bf16x8*)&up[k0],
                                                   *(const bf16x8*)&wp[k0], acc0, 0, 0, 0);
    acc1 = __builtin_amdgcn_mfma_f32_16x16x32_bf16(*(const bf16x8*)&up[k0 + 32],
                                                   *(const bf16x8*)&wp[k0 + 32], acc1, 0, 0, 0);
  }
  const int rbase = (lane >> 4) * 4;
#pragma unroll
  for (int rr = 0; rr < 4; rr++) {
    int bi = mt * 16 + rbase + rr;
    int d = h * 64 + dt * 16 + r16;
    g.ob[(size_t)bi * INNER_ + d] = f2b(acc0[rr] + acc1[rr]);
  }
}

// ================================ host =====================================
extern "C" void kernel_launch(void* const* d_in, const int* in_sizes, int n_in,
                              void* d_out, int out_size, void* d_ws, size_t ws_size,
                              hipStream_t stream) {
  const float* sm_tokens = (const float*)d_in[0];
  const float* lg_tokens = (const float*)d_in[1];
  const float* a_pin_w  = (const float*)d_in[2];  const float* a_pin_b  = (const float*)d_in[3];
  const float* a_ng     = (const float*)d_in[4];  const float* a_nb     = (const float*)d_in[5];
  const float* a_wq     = (const float*)d_in[6];  const float* a_wkv    = (const float*)d_in[7];
  const float* a_wo     = (const float*)d_in[8];  const float* a_wob    = (const float*)d_in[9];
  const float* a_pout_w = (const float*)d_in[10]; const float* a_pout_b = (const float*)d_in[11];
  const float* b_pin_w  = (const float*)d_in[12]; const float* b_pin_b  = (const float*)d_in[13];
  const float* b_ng     = (const float*)d_in[14]; const float* b_nb     = (const float*)d_in[15];
  const float* b_wq     = (const float*)d_in[16]; const float* b_wkv    = (const float*)d_in[17];
  const float* b_wo     = (const float*)d_in[18]; const float* b_wob    = (const float*)d_in[19];
  const float* b_pout_w = (const float*)d_in[20]; const float* b_pout_b = (const float*)d_in[21];

  float* out = (float*)d_out;
  char* ws = (char*)d_ws;
  size_t off = 0;
  auto alloc = [&](size_t bytes) -> void* {
    void* pt = ws + off;
    off += (bytes + 255) & ~(size_t)255;
    return pt;
  };
  unsigned short* Abf_lg = (unsigned short*)alloc(((size_t)B_ * NLG_ + 32) * LG_ * 2);
  unsigned short* Abf_sm = (unsigned short*)alloc(((size_t)B_ * NSM_ + 32) * SM_ * 2);
  unsigned short* xT_lg  = (unsigned short*)alloc((size_t)B_ * LG_ * 224 * 2);
  unsigned short* xT_sm  = (unsigned short*)alloc((size_t)B_ * SM_ * 416 * 2);
  unsigned short* WTv_a  = (unsigned short*)alloc((size_t)4 * 1024 * LG_ * 2);
  unsigned short* WTv_b  = (unsigned short*)alloc((size_t)4 * 1024 * SM_ * 2);
  unsigned short* wkvnb_a = (unsigned short*)alloc((size_t)4 * LG_ * 1024 * 2);
  unsigned short* wkvnb_b = (unsigned short*)alloc((size_t)4 * SM_ * 1024 * 2);
  unsigned short* WTpin_a = (unsigned short*)alloc((size_t)4 * SM_ * LG_ * 2);
  unsigned short* WTpin_b = (unsigned short*)alloc((size_t)4 * LG_ * SM_ * 2);
  unsigned short* WTwq_a  = (unsigned short*)alloc((size_t)4 * LG_ * INNER_ * 2);
  unsigned short* WTwq_b  = (unsigned short*)alloc((size_t)4 * SM_ * INNER_ * 2);
  unsigned short* WTwo_a  = (unsigned short*)alloc((size_t)4 * INNER_ * LG_ * 2);
  unsigned short* WTwo_b  = (unsigned short*)alloc((size_t)4 * INNER_ * SM_ * 2);
  unsigned short* WTpout_a = (unsigned short*)alloc((size_t)4 * LG_ * SM_ * 2);
  unsigned short* WTpout_b = (unsigned short*)alloc((size_t)4 * SM_ * LG_ * 2);
  unsigned short* qt_a = (unsigned short*)alloc((size_t)B_ * 16 * LG_ * 2);
  unsigned short* qt_b = (unsigned short*)alloc((size_t)B_ * 16 * SM_ * 2);
  float* S_a = (float*)alloc((size_t)B_ * 16 * SSTR * 4);
  float* S_b = (float*)alloc((size_t)B_ * 16 * SSTR * 4);
  unsigned short* p_a = (unsigned short*)alloc((size_t)B_ * 16 * PSTR * 2);
  unsigned short* p_b = (unsigned short*)alloc((size_t)B_ * 16 * PSTR * 2);
  unsigned short* u_a  = (unsigned short*)alloc((size_t)B_ * 16 * LG_ * 2);
  unsigned short* u_b  = (unsigned short*)alloc((size_t)B_ * 16 * SM_ * 2);
  float* cls_sm = (float*)alloc((size_t)B_ * SM_ * 4);
  float* cls_lg = (float*)alloc((size_t)B_ * LG_ * 4);
  unsigned short* clsb_sm = (unsigned short*)alloc((size_t)B_ * SM_ * 2);
  unsigned short* clsb_lg = (unsigned short*)alloc((size_t)B_ * LG_ * 2);
  float* xbuf_a = (float*)alloc((size_t)B_ * LG_ * 4);
  float* xbuf_b = (float*)alloc((size_t)B_ * SM_ * 4);
  unsigned short* xnb_a = (unsigned short*)alloc((size_t)B_ * LG_ * 2);
  unsigned short* xnb_b = (unsigned short*)alloc((size_t)B_ * SM_ * 2);
  float* qbuf_a = (float*)alloc((size_t)B_ * INNER_ * 4);
  float* qbuf_b = (float*)alloc((size_t)B_ * INNER_ * 4);
  unsigned short* qb16_a = (unsigned short*)alloc((size_t)B_ * INNER_ * 2);
  unsigned short* qb16_b = (unsigned short*)alloc((size_t)B_ * INNER_ * 2);
  unsigned short* obufb_a = (unsigned short*)alloc((size_t)B_ * INNER_ * 2);
  unsigned short* obufb_b = (unsigned short*)alloc((size_t)B_ * INNER_ * 2);
  unsigned short* t1b_a = (unsigned short*)alloc((size_t)B_ * LG_ * 2);
  unsigned short* t1b_b = (unsigned short*)alloc((size_t)B_ * SM_ * 2);
  unsigned short* zb = (unsigned short*)alloc(1024 * 2);   // zero row
  (void)ws_size; (void)in_sizes; (void)n_in; (void)out_size;

  const size_t sm_elems = (size_t)B_ * (NSM_ + 1) * SM_;

  // ---- setup1: weight transposes/copies + token pass (one dispatch)
  CC2 ca{sm_tokens, out, Abf_sm, cls_sm, clsb_sm, NSM_ + 1, SM_ / 4, 7,
         (int)(sm_elems / 4)};
  CC2 cb{lg_tokens, out + sm_elems, Abf_lg, cls_lg, clsb_lg, NLG_ + 1, LG_ / 4, 8,
         (int)((size_t)B_ * (NLG_ + 1) * LG_ / 4)};
  WTArgs W;
  // {src, dstT, dstS, K, Ntiles, srcStride, colOff}
  W.d[0]  = {a_wkv,    nullptr,  wkvnb_a, LG_,   16, 2048, 0};     // K-half straight copy
  W.d[1]  = {a_wkv,    WTv_a,    nullptr, LG_,   16, 2048, 1024};  // V-half transpose
  W.d[2]  = {b_wkv,    nullptr,  wkvnb_b, SM_,   16, 2048, 0};
  W.d[3]  = {b_wkv,    WTv_b,    nullptr, SM_,   16, 2048, 1024};
  W.d[4]  = {a_pin_w,  WTpin_a,  nullptr, SM_,   16, 1024, 0};
  W.d[5]  = {b_pin_w,  WTpin_b,  nullptr, LG_,    8,  512, 0};
  W.d[6]  = {a_wq,     WTwq_a,   nullptr, LG_,   16, 1024, 0};
  W.d[7]  = {b_wq,     WTwq_b,   nullptr, SM_,   16, 1024, 0};
  W.d[8]  = {a_wo,     WTwo_a,   nullptr, INNER_,16, 1024, 0};
  W.d[9]  = {b_wo,     WTwo_b,   nullptr, INNER_, 8,  512, 0};
  W.d[10] = {a_pout_w, WTpout_a, nullptr, LG_,    8,  512, 0};
  W.d[11] = {b_pout_w, WTpout_b, nullptr, SM_,   16, 1024, 0};
  W.cum[0] = 0;
  for (int i = 0; i < 12; i++)
    W.cum[i + 1] = W.cum[i] + (W.d[i].K / 64) * W.d[i].Ntiles * 4;
  setup1<<<W.cum[12] + 2048, 256, 0, stream>>>(ca, cb, W, W.cum[12], zb);
  // ---- setup2: x^T (needs Abf from setup1)
  TXArgs txa{Abf_lg, xT_lg, NLG_, LG_, 224, LG_ / 64, 4, B_ * (LG_ / 64) * 4};
  TXArgs txb{Abf_sm, xT_sm, NSM_, SM_, 416, SM_ / 64, 7, B_ * (SM_ / 64) * 7};
  setup2<<<txa.nblk + txb.nblk, 256, 0, stream>>>(txa, txb);

  for (int l = 0; l < 4; l++) {
    const unsigned short* WTpin_al = WTpin_a + (size_t)l * SM_ * LG_;
    const unsigned short* WTpin_bl = WTpin_b + (size_t)l * LG_ * SM_;
    const unsigned short* WTwq_al  = WTwq_a  + (size_t)l * LG_ * INNER_;
    const unsigned short* WTwq_bl  = WTwq_b  + (size_t)l * SM_ * INNER_;
    const unsigned short* WTv_al   = WTv_a   + (size_t)l * 1024 * LG_;
    const unsigned short* WTv_bl   = WTv_b   + (size_t)l * 1024 * SM_;
    const unsigned short* wkvnb_al = wkvnb_a + (size_t)l * LG_ * 1024;
    const unsigned short* wkvnb_bl = wkvnb_b + (size_t)l * SM_ * 1024;
    const unsigned short* WTwo_al  = WTwo_a  + (size_t)l * INNER_ * LG_;
    const unsigned short* WTwo_bl  = WTwo_b  + (size_t)l * INNER_ * SM_;
    const unsigned short* WTpout_al = WTpout_a + (size_t)l * LG_ * SM_;
    const unsigned short* WTpout_bl = WTpout_b + (size_t)l * SM_ * LG_;

    // pin
    SGArgs Gp; Gp.nd = 2;
    Gp.d[0] = {clsb_sm, WTpin_al, a_pin_b + (size_t)l * LG_, xbuf_a, nullptr, nullptr, SM_, LG_, nullptr, 0};
    Gp.d[1] = {clsb_lg, WTpin_bl, b_pin_b + (size_t)l * SM_, xbuf_b, nullptr, nullptr, LG_, SM_, nullptr, 0};
    Gp.cum[0] = 0; Gp.cum[1] = LG_ / 16; Gp.cum[2] = LG_ / 16 + SM_ / 16;
    sg_wide<<<Gp.cum[2], 256, 0, stream>>>(Gp);
    // ln (+ scatter xn into xT col Nctx)
    LNArgs la{xbuf_a, xnb_a, a_ng + (size_t)l * LG_, a_nb + (size_t)l * LG_, LG_, xT_lg, 224, NLG_};
    LNArgs lb{xbuf_b, xnb_b, b_ng + (size_t)l * SM_, b_nb + (size_t)l * SM_, SM_, xT_sm, 416, NSM_};
    ln2<<<128, 256, 0, stream>>>(la, lb);
    // q only (f32 + bf16 mirror)
    SGArgs Gq; Gq.nd = 2;
    Gq.d[0] = {xnb_a, WTwq_al, nullptr, qbuf_a, qb16_a, nullptr, LG_, INNER_, nullptr, 0};
    Gq.d[1] = {xnb_b, WTwq_bl, nullptr, qbuf_b, qb16_b, nullptr, SM_, INNER_, nullptr, 0};
    Gq.cum[0] = 0; Gq.cum[1] = 64; Gq.cum[2] = 128;
    sg_wide<<<128, 256, 0, stream>>>(Gq);
    // q~ (MFMA over bf16 straight wkv K-half)
    QTArgs qa{qb16_a, wkvnb_al, qt_a, LG_, LG_ / 16, 16 * (LG_ / 16)};
    QTArgs qb{qb16_b, wkvnb_bl, qt_b, SM_, SM_ / 16, 16 * (SM_ / 16)};
    qtilde3<<<qa.nblk + qb.nblk, 256, 0, stream>>>(qa, qb);
    // S = q~ . x^T  (cls row included; XCD-swizzled)
    SArgs sa{qt_a, Abf_lg, xnb_a, zb, S_a, LG_, NLG_, 14, 4, B_ * 4};
    SArgs sb{qt_b, Abf_sm, xnb_b, zb, S_b, SM_, NSM_, 26, 7, B_ * 7};
    s_gemm<<<sa.nblk + sb.nblk, 256, 0, stream>>>(sa, sb);
    // softmax -> p (once per (b,h); cls = row Nctx)
    SMArgs ma{S_a, p_a, NLG_ + 1, 224};
    SMArgs mb{S_b, p_b, NSM_ + 1, 416};
    softmax_p2<<<dim3(H_, B_, 2), 256, 0, stream>>>(ma, mb);
    // u = p . x  (1D grid, XCD-swizzled; includes cls term)
    UG ua{p_a, xT_lg, u_a, LG_, 224, 224, LG_ / 64};
    UG ub{p_b, xT_sm, u_b, SM_, 416, 416, SM_ / 64};
    ugemm2<<<1536, 256, 0, stream>>>(ua, ub);
    // o = u . Wv
    OArgs oa{u_a, WTv_al, obufb_a, LG_};
    OArgs ob{u_b, WTv_bl, obufb_b, SM_};
    ogemm_w<<<128, 256, 0, stream>>>(oa, ob);
    // wo
    SGArgs Gw; Gw.nd = 2;
    Gw.d[0] = {obufb_a, WTwo_al, a_wob + (size_t)l * LG_, nullptr, t1b_a, nullptr, INNER_, LG_, nullptr, 0};
    Gw.d[1] = {obufb_b, WTwo_bl, b_wob + (size_t)l * SM_, nullptr, t1b_b, nullptr, INNER_, SM_, nullptr, 0};
    Gw.cum[0] = 0; Gw.cum[1] = LG_ / 16; Gw.cum[2] = LG_ / 16 + SM_ / 16;
    sg_wide<<<Gw.cum[2], 256, 0, stream>>>(Gw);
    // pout + residual; on the last layer also write cls rows straight to out
    float* outF_a = (l == 3) ? out : nullptr;
    float* outF_b = (l == 3) ? out + sm_elems : nullptr;
    SGArgs Gr; Gr.nd = 2;
    Gr.d[0] = {t1b_a, WTpout_al, a_pout_b + (size_t)l * SM_, cls_sm, clsb_sm, cls_sm, LG_, SM_,
               outF_a, (NSM_ + 1) * SM_};
    Gr.d[1] = {t1b_b, WTpout_bl, b_pout_b + (size_t)l * LG_, cls_lg, clsb_lg, cls_lg, SM_, LG_,
               outF_b, (NLG_ + 1) * LG_};
    Gr.cum[0] = 0; Gr.cum[1] = SM_ / 16; Gr.cum[2] = SM_ / 16 + LG_ / 16;
    sg_wide<<<Gr.cum[2], 256, 0, stream>>>(Gr);
  }
}